// Round 4
// baseline (267.420 us; speedup 1.0000x reference)
//
#include <hip/hip_runtime.h>

#define NH 16
#define HD 64
#define TSEQ 2048
#define DMODEL 1024

typedef __attribute__((ext_vector_type(8))) short short8;
typedef __attribute__((ext_vector_type(4))) float f32x4;

static __device__ __forceinline__ unsigned short f2bf(float f) {
    unsigned u = __builtin_bit_cast(unsigned, f);
    u += 0x7FFF + ((u >> 16) & 1);
    return (unsigned short)(u >> 16);
}

static __device__ __forceinline__ unsigned pk2(float a, float b) {
    unsigned ua = __builtin_bit_cast(unsigned, a);
    unsigned ub = __builtin_bit_cast(unsigned, b);
    return ((ua + 0x8000u) >> 16) | (((ub + 0x8000u) >> 16) << 16);
}

// ---------------- cast f32 -> bf16 (vectorized, n multiple of 4) ----------------
__global__ __launch_bounds__(256) void cast_f32_bf16(const float* __restrict__ src,
                                                     unsigned short* __restrict__ dst, int n4) {
    int i = blockIdx.x * 256 + threadIdx.x;
    if (i >= n4) return;
    float4 v = reinterpret_cast<const float4*>(src)[i];
    ushort4 o;
    o.x = f2bf(v.x); o.y = f2bf(v.y); o.z = f2bf(v.z); o.w = f2bf(v.w);
    reinterpret_cast<ushort4*>(dst)[i] = o;
}

// ---------------- m97-style GEMM mainloop: C[128x128] = A[M][K] * Bt[N][K]^T ----------------
static __device__ __forceinline__ void gemm_mainloop(const unsigned short* __restrict__ A,
                                                     const unsigned short* __restrict__ Bt,
                                                     int m0, int n0, int K,
                                                     unsigned short* As, unsigned short* Bs,
                                                     f32x4 acc[4][4]) {
    const int tid = threadIdx.x;
    const int lane = tid & 63;
    const int w = tid >> 6;
    const int wr = w >> 1, wc = w & 1;
    const int lrow = lane >> 2;          // 0..15
    const int lcol = (lane & 3) * 8;     // 0,8,16,24  (ushort units)

    f32x4 zero = {0.f, 0.f, 0.f, 0.f};
#pragma unroll
    for (int i = 0; i < 4; i++)
#pragma unroll
        for (int j = 0; j < 4; j++) acc[i][j] = zero;

    for (int k0 = 0; k0 < K; k0 += 32) {
        __syncthreads();
#pragma unroll
        for (int c = w; c < 8; c += 4) {
            int row = c * 16 + lrow;
            __builtin_amdgcn_global_load_lds(
                (const __attribute__((address_space(1))) void*)(A + (size_t)(m0 + row) * K + k0 + lcol),
                (__attribute__((address_space(3))) void*)(As + c * 512), 16, 0, 0);
            __builtin_amdgcn_global_load_lds(
                (const __attribute__((address_space(1))) void*)(Bt + (size_t)(n0 + row) * K + k0 + lcol),
                (__attribute__((address_space(3))) void*)(Bs + c * 512), 16, 0, 0);
        }
        __syncthreads();

        const int ko = (lane >> 4) * 8;
        short8 a[4], b[4];
#pragma unroll
        for (int i = 0; i < 4; i++)
            a[i] = *(const short8*)(As + (wr * 64 + i * 16 + (lane & 15)) * 32 + ko);
#pragma unroll
        for (int j = 0; j < 4; j++)
            b[j] = *(const short8*)(Bs + (wc * 64 + j * 16 + (lane & 15)) * 32 + ko);
#pragma unroll
        for (int i = 0; i < 4; i++)
#pragma unroll
            for (int j = 0; j < 4; j++)
                acc[i][j] = __builtin_amdgcn_mfma_f32_16x16x32_bf16(a[i], b[j], acc[i][j], 0, 0, 0);
    }
}

// ---------------- QKV projection ----------------
// Q is pre-scaled by 0.125 * log2(e) so attention can use exp2 with no per-element scaling.
#define QSCALE 0.180336880f
__global__ __launch_bounds__(256) void gemm_qkv(const unsigned short* __restrict__ xb,
                                                const unsigned short* __restrict__ Wqb,
                                                const unsigned short* __restrict__ Wkb,
                                                const unsigned short* __restrict__ Wvb,
                                                unsigned short* __restrict__ Q,
                                                unsigned short* __restrict__ K,
                                                unsigned short* __restrict__ Vt) {
    __shared__ __attribute__((aligned(16))) unsigned short As[128 * 32];
    __shared__ __attribute__((aligned(16))) unsigned short Bs[128 * 32];
    const int m0 = blockIdx.x * 128;
    const int n0 = blockIdx.y * 128;
    const int z = blockIdx.z;
    const unsigned short* Bt = (z == 0) ? Wqb : ((z == 1) ? Wkb : Wvb);
    unsigned short* out = (z == 0) ? Q : ((z == 1) ? K : Vt);

    f32x4 acc[4][4];
    gemm_mainloop(xb, Bt, m0, n0, DMODEL, As, Bs, acc);

    const int tid = threadIdx.x, lane = tid & 63, w = tid >> 6;
    const int wr = w >> 1, wc = w & 1;
    const float sc = (z == 0) ? QSCALE : 1.0f;
#pragma unroll
    for (int i = 0; i < 4; i++)
#pragma unroll
        for (int j = 0; j < 4; j++)
#pragma unroll
            for (int r = 0; r < 4; r++) {
                int row = m0 + wr * 64 + i * 16 + (lane >> 4) * 4 + r;  // b*2048 + t
                int col = n0 + wc * 64 + j * 16 + (lane & 15);          // h*64 + d
                int b = row >> 11, t = row & 2047;
                int h = col >> 6, d = col & 63;
                unsigned short v = f2bf(acc[i][j][r] * sc);
                if (z == 2)
                    out[(((size_t)(b * NH + h)) * HD + d) * TSEQ + t] = v;
                else
                    out[(((size_t)(b * NH + h)) * TSEQ + t) * HD + d] = v;
            }
}

// ---------------- output projection ----------------
__global__ __launch_bounds__(256) void gemm_out(const unsigned short* __restrict__ ctx,
                                                const unsigned short* __restrict__ Wob,
                                                const float* __restrict__ bo,
                                                float* __restrict__ out) {
    __shared__ __attribute__((aligned(16))) unsigned short As[128 * 32];
    __shared__ __attribute__((aligned(16))) unsigned short Bs[128 * 32];
    const int m0 = blockIdx.x * 128;
    const int n0 = blockIdx.y * 128;

    f32x4 acc[4][4];
    gemm_mainloop(ctx, Wob, m0, n0, DMODEL, As, Bs, acc);

    const int tid = threadIdx.x, lane = tid & 63, w = tid >> 6;
    const int wr = w >> 1, wc = w & 1;
#pragma unroll
    for (int i = 0; i < 4; i++)
#pragma unroll
        for (int j = 0; j < 4; j++)
#pragma unroll
            for (int r = 0; r < 4; r++) {
                int row = m0 + wr * 64 + i * 16 + (lane >> 4) * 4 + r;
                int col = n0 + wc * 64 + j * 16 + (lane & 15);
                out[(size_t)row * DMODEL + col] = acc[i][j][r] + bo[col];
            }
}

// ---------------- flash attention (causal), Q-tile 128, KV-tile 64, 4 waves ----------------
// S^T structure: st = mfma(K, Q) so q = lane&15 (lane-local rows), k = cb*16+4*lg+r.
// Softmax: in-register over 16 k + 2 shfl. P written as packed b64 rows [q][k] (stride 76).
// PV computed as O^T = mfma(Vt-frag, P-frag). Epilogue transposes O^T via LDS.
__global__ __launch_bounds__(256, 4) void attn(const unsigned short* __restrict__ Qg,
                                               const unsigned short* __restrict__ Kg,
                                               const unsigned short* __restrict__ Vg,
                                               unsigned short* __restrict__ ctx) {
    __shared__ __attribute__((aligned(16))) unsigned short Ks[64][72];
    __shared__ __attribute__((aligned(16))) unsigned short Vs[64][72];
    __shared__ __attribute__((aligned(16))) unsigned short Pl[128][76];

    const int tid = threadIdx.x, lane = tid & 63, w = tid >> 6;
    const int wq = w * 32;
    const int lg = lane >> 4;        // 16-lane group id 0..3
    const int ll = lane & 15;
    const int bh = blockIdx.x;       // b*16+h
    const int q0 = (gridDim.y - 1 - blockIdx.y) * 128;   // heavy tiles first (LPT)
    const unsigned short* Qh = Qg + (size_t)bh * TSEQ * HD;
    const unsigned short* Kh = Kg + (size_t)bh * TSEQ * HD;
    const unsigned short* Vh = Vg + (size_t)bh * HD * TSEQ;

    // Q B-fragments straight from global: Q[q=wq+rb*16+ll][d=ks*32+lg*8+j]
    short8 qf[2][2];
#pragma unroll
    for (int rb = 0; rb < 2; rb++)
#pragma unroll
        for (int ks = 0; ks < 2; ks++)
            qf[rb][ks] = *(const short8*)(Qh + (size_t)(q0 + wq + rb * 16 + ll) * HD + ks * 32 + lg * 8);

    float mrun[2] = {-1e30f, -1e30f}, lrun[2] = {0.f, 0.f};
    f32x4 zero = {0.f, 0.f, 0.f, 0.f};
    // O^T accumulators: o_t[rb][db], D[row=4lg+r -> d=db*16+4lg+r][col=ll -> q=wq+rb*16+ll]
    f32x4 o_t[2][4];
#pragma unroll
    for (int rb = 0; rb < 2; rb++)
#pragma unroll
        for (int db = 0; db < 4; db++) o_t[rb][db] = zero;

    // async staging: thread covers rows sr and sr+32, 16B each
    const int sr = tid >> 3;          // 0..31
    const int sc = (tid & 7) * 8;     // ushort offset 0..56
    short8 kreg0, kreg1, vreg0, vreg1;
    {
        kreg0 = *(const short8*)(Kh + (size_t)(sr) * HD + sc);
        kreg1 = *(const short8*)(Kh + (size_t)(sr + 32) * HD + sc);
        vreg0 = *(const short8*)(Vh + (size_t)sr * TSEQ + sc);
        vreg1 = *(const short8*)(Vh + (size_t)(sr + 32) * TSEQ + sc);
    }

    const int nkv = q0 / 64 + 2;
    for (int kt = 0; kt < nkv; kt++) {
        const int kv0 = kt * 64;
        __syncthreads();   // previous tile's readers done with Ks/Vs
        *(short8*)&Ks[sr][sc] = kreg0;
        *(short8*)&Ks[sr + 32][sc] = kreg1;
        *(short8*)&Vs[sr][sc] = vreg0;
        *(short8*)&Vs[sr + 32][sc] = vreg1;
        if (kt + 1 < nkv) {           // next tile's loads hide under compute
            const int nv0 = kv0 + 64;
            kreg0 = *(const short8*)(Kh + (size_t)(nv0 + sr) * HD + sc);
            kreg1 = *(const short8*)(Kh + (size_t)(nv0 + sr + 32) * HD + sc);
            vreg0 = *(const short8*)(Vh + (size_t)sr * TSEQ + nv0 + sc);
            vreg1 = *(const short8*)(Vh + (size_t)(sr + 32) * TSEQ + nv0 + sc);
        }
        __syncthreads();   // staged tile visible

        // S^T = K * Q^T : st[rb][cb], D[row=4lg+r -> kv=cb*16+4lg+r][col=ll -> q]
        f32x4 st[2][4];
#pragma unroll
        for (int rb = 0; rb < 2; rb++)
#pragma unroll
            for (int cb = 0; cb < 4; cb++) st[rb][cb] = zero;
#pragma unroll
        for (int ks = 0; ks < 2; ks++) {
            short8 afrag[4];
#pragma unroll
            for (int cb = 0; cb < 4; cb++)
                afrag[cb] = *(const short8*)&Ks[cb * 16 + ll][ks * 32 + lg * 8];
#pragma unroll
            for (int rb = 0; rb < 2; rb++)
#pragma unroll
                for (int cb = 0; cb < 4; cb++)
                    st[rb][cb] = __builtin_amdgcn_mfma_f32_16x16x32_bf16(afrag[cb], qf[rb][ks], st[rb][cb], 0, 0, 0);
        }

        // causal mask (near-diagonal tiles only)
        if (kv0 + 63 > q0) {
#pragma unroll
            for (int rb = 0; rb < 2; rb++)
#pragma unroll
                for (int cb = 0; cb < 4; cb++)
#pragma unroll
                    for (int r = 0; r < 4; r++) {
                        int kvl = cb * 16 + lg * 4 + r;
                        int ql = wq + rb * 16 + ll;
                        if (kv0 + kvl > q0 + ql) st[rb][cb][r] = -1e30f;
                    }
        }

        // row max: 16 in-register values per (rb), then 2 shfl over the lg axis
        float mx[2];
#pragma unroll
        for (int rb = 0; rb < 2; rb++) {
            float a0 = fmaxf(fmaxf(st[rb][0][0], st[rb][0][1]), fmaxf(st[rb][0][2], st[rb][0][3]));
            float a1 = fmaxf(fmaxf(st[rb][1][0], st[rb][1][1]), fmaxf(st[rb][1][2], st[rb][1][3]));
            float a2 = fmaxf(fmaxf(st[rb][2][0], st[rb][2][1]), fmaxf(st[rb][2][2], st[rb][2][3]));
            float a3 = fmaxf(fmaxf(st[rb][3][0], st[rb][3][1]), fmaxf(st[rb][3][2], st[rb][3][3]));
            float m = fmaxf(fmaxf(a0, a1), fmaxf(a2, a3));
            m = fmaxf(m, __shfl_xor(m, 16));
            m = fmaxf(m, __shfl_xor(m, 32));
            mx[rb] = m;
        }
        // defer-max (THR=8 in exp2 scale -> P <= 256)
        float need = fmaxf(mx[0] - mrun[0], mx[1] - mrun[1]);
        if (__any(need > 8.f)) {
#pragma unroll
            for (int rb = 0; rb < 2; rb++) {
                float mold = mrun[rb];
                float mn = fmaxf(mold, mx[rb]);
                float rs = __builtin_amdgcn_exp2f(mold - mn);
                mrun[rb] = mn;
                lrun[rb] *= rs;
#pragma unroll
                for (int db = 0; db < 4; db++)
#pragma unroll
                    for (int r = 0; r < 4; r++) o_t[rb][db][r] *= rs;
            }
        }
        // P = exp2(S^T - m): lane's 4 consecutive k -> one packed b64 write per (rb,cb)
#pragma unroll
        for (int rb = 0; rb < 2; rb++) {
            float sum = 0.f;
#pragma unroll
            for (int cb = 0; cb < 4; cb++) {
                float p0 = __builtin_amdgcn_exp2f(st[rb][cb][0] - mrun[rb]);
                float p1 = __builtin_amdgcn_exp2f(st[rb][cb][1] - mrun[rb]);
                float p2 = __builtin_amdgcn_exp2f(st[rb][cb][2] - mrun[rb]);
                float p3 = __builtin_amdgcn_exp2f(st[rb][cb][3] - mrun[rb]);
                sum += (p0 + p1) + (p2 + p3);
                uint2 pw;
                pw.x = pk2(p0, p1);
                pw.y = pk2(p2, p3);
                *(uint2*)&Pl[wq + rb * 16 + ll][cb * 16 + lg * 4] = pw;
            }
            sum += __shfl_xor(sum, 16);
            sum += __shfl_xor(sum, 32);
            lrun[rb] += sum;
        }
        // wave-private P: drain this wave's LDS ops, pin ordering (rule 18)
        asm volatile("s_waitcnt lgkmcnt(0)" ::: "memory");
        __builtin_amdgcn_sched_barrier(0);

        // O^T += V^T * P^T : A = Vt-frag, B = P-frag
#pragma unroll
        for (int ks = 0; ks < 2; ks++) {
            short8 pa[2], va[4];
#pragma unroll
            for (int rb = 0; rb < 2; rb++)
                pa[rb] = *(const short8*)&Pl[wq + rb * 16 + ll][ks * 32 + lg * 8];
#pragma unroll
            for (int db = 0; db < 4; db++)
                va[db] = *(const short8*)&Vs[db * 16 + ll][ks * 32 + lg * 8];
#pragma unroll
            for (int rb = 0; rb < 2; rb++)
#pragma unroll
                for (int db = 0; db < 4; db++)
                    o_t[rb][db] = __builtin_amdgcn_mfma_f32_16x16x32_bf16(va[db], pa[rb], o_t[rb][db], 0, 0, 0);
        }
    }

    // epilogue: scale by 1/l (lane-uniform!), transpose O^T via wave-private Pl slice, store
    const int b = bh >> 4, h = bh & 15;
#pragma unroll
    for (int rb = 0; rb < 2; rb++) {
        float linv = 1.f / lrun[rb];
#pragma unroll
        for (int db = 0; db < 4; db++) {
            float v0 = o_t[rb][db][0] * linv, v1 = o_t[rb][db][1] * linv;
            float v2 = o_t[rb][db][2] * linv, v3 = o_t[rb][db][3] * linv;
            uint2 pw;
            pw.x = pk2(v0, v1);
            pw.y = pk2(v2, v3);
            *(uint2*)&Pl[wq + rb * 16 + ll][db * 16 + lg * 4] = pw;
        }
    }
    asm volatile("s_waitcnt lgkmcnt(0)" ::: "memory");
    __builtin_amdgcn_sched_barrier(0);
#pragma unroll
    for (int rb = 0; rb < 2; rb++)
#pragma unroll
        for (int half = 0; half < 2; half++) {
            short8 v = *(const short8*)&Pl[wq + rb * 16 + ll][half * 32 + lg * 8];
            size_t row = (size_t)(b * TSEQ + q0 + wq + rb * 16 + ll);
            *(short8*)(ctx + (row * NH + h) * HD + half * 32 + lg * 8) = v;
        }
}

extern "C" void kernel_launch(void* const* d_in, const int* in_sizes, int n_in,
                              void* d_out, int out_size, void* d_ws, size_t ws_size,
                              hipStream_t stream) {
    const float* x  = (const float*)d_in[0];
    const float* Wq = (const float*)d_in[1];
    const float* Wk = (const float*)d_in[2];
    const float* Wv = (const float*)d_in[3];
    const float* Wo = (const float*)d_in[4];
    const float* bo = (const float*)d_in[5];
    float* out = (float*)d_out;

    char* ws = (char*)d_ws;
    unsigned short* xb   = (unsigned short*)(ws);             // 16,777,216 B
    unsigned short* Wqb  = (unsigned short*)(ws + 16777216);
    unsigned short* Wkb  = (unsigned short*)(ws + 18874368);
    unsigned short* Wvb  = (unsigned short*)(ws + 20971520);
    unsigned short* Wob  = (unsigned short*)(ws + 23068672);
    unsigned short* Qb   = (unsigned short*)(ws + 25165824);  // [B,H,T,hd] bf16 (pre-scaled)
    unsigned short* Kb   = (unsigned short*)(ws + 41943040);  // [B,H,T,hd]
    unsigned short* Vtb  = (unsigned short*)(ws + 58720256);  // [B,H,hd,T]
    unsigned short* ctxb = (unsigned short*)(ws + 75497472);  // [B,T,H,hd]

    cast_f32_bf16<<<8192, 256, 0, stream>>>(x, xb, 2097152);
    cast_f32_bf16<<<1024, 256, 0, stream>>>(Wq, Wqb, 262144);
    cast_f32_bf16<<<1024, 256, 0, stream>>>(Wk, Wkb, 262144);
    cast_f32_bf16<<<1024, 256, 0, stream>>>(Wv, Wvb, 262144);
    cast_f32_bf16<<<1024, 256, 0, stream>>>(Wo, Wob, 262144);

    gemm_qkv<<<dim3(64, 8, 3), 256, 0, stream>>>(xb, Wqb, Wkb, Wvb, Qb, Kb, Vtb);
    attn<<<dim3(64, 16), 256, 0, stream>>>(Qb, Kb, Vtb, ctxb);
    gemm_out<<<dim3(64, 8), 256, 0, stream>>>(ctxb, Wob, bo, out);
}

// Round 5
// 204.789 us; speedup vs baseline: 1.3058x; 1.3058x over previous
//
#include <hip/hip_runtime.h>

#define NH 16
#define HD 64
#define TSEQ 2048
#define DMODEL 1024

typedef __attribute__((ext_vector_type(8))) short short8;
typedef __attribute__((ext_vector_type(4))) float f32x4;

static __device__ __forceinline__ unsigned short f2bf(float f) {
    unsigned u = __builtin_bit_cast(unsigned, f);
    u += 0x7FFF + ((u >> 16) & 1);
    return (unsigned short)(u >> 16);
}

static __device__ __forceinline__ unsigned pk2(float a, float b) {
    unsigned ua = __builtin_bit_cast(unsigned, a);
    unsigned ub = __builtin_bit_cast(unsigned, b);
    return ((ua + 0x8000u) >> 16) | (((ub + 0x8000u) >> 16) << 16);
}

// ---------------- cast f32 -> bf16 (vectorized, n multiple of 4) ----------------
__global__ __launch_bounds__(256) void cast_f32_bf16(const float* __restrict__ src,
                                                     unsigned short* __restrict__ dst, int n4) {
    int i = blockIdx.x * 256 + threadIdx.x;
    if (i >= n4) return;
    float4 v = reinterpret_cast<const float4*>(src)[i];
    ushort4 o;
    o.x = f2bf(v.x); o.y = f2bf(v.y); o.z = f2bf(v.z); o.w = f2bf(v.w);
    reinterpret_cast<ushort4*>(dst)[i] = o;
}

// ---------------- m97-style GEMM mainloop: C[128x128] = A[M][K] * Bt[N][K]^T ----------------
static __device__ __forceinline__ void gemm_mainloop(const unsigned short* __restrict__ A,
                                                     const unsigned short* __restrict__ Bt,
                                                     int m0, int n0, int K,
                                                     unsigned short* As, unsigned short* Bs,
                                                     f32x4 acc[4][4]) {
    const int tid = threadIdx.x;
    const int lane = tid & 63;
    const int w = tid >> 6;
    const int wr = w >> 1, wc = w & 1;
    const int lrow = lane >> 2;          // 0..15
    const int lcol = (lane & 3) * 8;     // 0,8,16,24  (ushort units)

    f32x4 zero = {0.f, 0.f, 0.f, 0.f};
#pragma unroll
    for (int i = 0; i < 4; i++)
#pragma unroll
        for (int j = 0; j < 4; j++) acc[i][j] = zero;

    for (int k0 = 0; k0 < K; k0 += 32) {
        __syncthreads();
#pragma unroll
        for (int c = w; c < 8; c += 4) {
            int row = c * 16 + lrow;
            __builtin_amdgcn_global_load_lds(
                (const __attribute__((address_space(1))) void*)(A + (size_t)(m0 + row) * K + k0 + lcol),
                (__attribute__((address_space(3))) void*)(As + c * 512), 16, 0, 0);
            __builtin_amdgcn_global_load_lds(
                (const __attribute__((address_space(1))) void*)(Bt + (size_t)(n0 + row) * K + k0 + lcol),
                (__attribute__((address_space(3))) void*)(Bs + c * 512), 16, 0, 0);
        }
        __syncthreads();

        const int ko = (lane >> 4) * 8;
        short8 a[4], b[4];
#pragma unroll
        for (int i = 0; i < 4; i++)
            a[i] = *(const short8*)(As + (wr * 64 + i * 16 + (lane & 15)) * 32 + ko);
#pragma unroll
        for (int j = 0; j < 4; j++)
            b[j] = *(const short8*)(Bs + (wc * 64 + j * 16 + (lane & 15)) * 32 + ko);
#pragma unroll
        for (int i = 0; i < 4; i++)
#pragma unroll
            for (int j = 0; j < 4; j++)
                acc[i][j] = __builtin_amdgcn_mfma_f32_16x16x32_bf16(a[i], b[j], acc[i][j], 0, 0, 0);
    }
}

// ---------------- QKV projection ----------------
// Q is pre-scaled by 0.125 * log2(e) so attention can use exp2 with no per-element scaling.
#define QSCALE 0.180336880f
__global__ __launch_bounds__(256) void gemm_qkv(const unsigned short* __restrict__ xb,
                                                const unsigned short* __restrict__ Wqb,
                                                const unsigned short* __restrict__ Wkb,
                                                const unsigned short* __restrict__ Wvb,
                                                unsigned short* __restrict__ Q,
                                                unsigned short* __restrict__ K,
                                                unsigned short* __restrict__ Vt) {
    __shared__ __attribute__((aligned(16))) unsigned short As[128 * 32];
    __shared__ __attribute__((aligned(16))) unsigned short Bs[128 * 32];
    const int m0 = blockIdx.x * 128;
    const int n0 = blockIdx.y * 128;
    const int z = blockIdx.z;
    const unsigned short* Bt = (z == 0) ? Wqb : ((z == 1) ? Wkb : Wvb);
    unsigned short* out = (z == 0) ? Q : ((z == 1) ? K : Vt);

    f32x4 acc[4][4];
    gemm_mainloop(xb, Bt, m0, n0, DMODEL, As, Bs, acc);

    const int tid = threadIdx.x, lane = tid & 63, w = tid >> 6;
    const int wr = w >> 1, wc = w & 1;
    const float sc = (z == 0) ? QSCALE : 1.0f;
#pragma unroll
    for (int i = 0; i < 4; i++)
#pragma unroll
        for (int j = 0; j < 4; j++)
#pragma unroll
            for (int r = 0; r < 4; r++) {
                int row = m0 + wr * 64 + i * 16 + (lane >> 4) * 4 + r;  // b*2048 + t
                int col = n0 + wc * 64 + j * 16 + (lane & 15);          // h*64 + d
                int b = row >> 11, t = row & 2047;
                int h = col >> 6, d = col & 63;
                unsigned short v = f2bf(acc[i][j][r] * sc);
                if (z == 2)
                    out[(((size_t)(b * NH + h)) * HD + d) * TSEQ + t] = v;
                else
                    out[(((size_t)(b * NH + h)) * TSEQ + t) * HD + d] = v;
            }
}

// ---------------- output projection ----------------
__global__ __launch_bounds__(256) void gemm_out(const unsigned short* __restrict__ ctx,
                                                const unsigned short* __restrict__ Wob,
                                                const float* __restrict__ bo,
                                                float* __restrict__ out) {
    __shared__ __attribute__((aligned(16))) unsigned short As[128 * 32];
    __shared__ __attribute__((aligned(16))) unsigned short Bs[128 * 32];
    const int m0 = blockIdx.x * 128;
    const int n0 = blockIdx.y * 128;

    f32x4 acc[4][4];
    gemm_mainloop(ctx, Wob, m0, n0, DMODEL, As, Bs, acc);

    const int tid = threadIdx.x, lane = tid & 63, w = tid >> 6;
    const int wr = w >> 1, wc = w & 1;
#pragma unroll
    for (int i = 0; i < 4; i++)
#pragma unroll
        for (int j = 0; j < 4; j++)
#pragma unroll
            for (int r = 0; r < 4; r++) {
                int row = m0 + wr * 64 + i * 16 + (lane >> 4) * 4 + r;
                int col = n0 + wc * 64 + j * 16 + (lane & 15);
                out[(size_t)row * DMODEL + col] = acc[i][j][r] + bo[col];
            }
}

// ---------------- flash attention (causal), Q-tile 128, KV-tile 64, 4 waves ----------------
// S^T structure: st = mfma(K, Q) so q = lane&15 (lane-local rows), k = cb*16+4*lg+r.
// Softmax: in-register over 16 k + 2 shfl. P written as packed b64 rows [q][k] (stride 76).
// PV computed as O^T = mfma(Vt-frag, P-frag). Epilogue transposes O^T via LDS.
// Raw s_barrier pipeline: next-tile global loads stay in flight across barriers (T4);
// only lgkmcnt is drained for ds_write visibility. No __launch_bounds__ min-waves (spills!).
__global__ __launch_bounds__(256) void attn(const unsigned short* __restrict__ Qg,
                                            const unsigned short* __restrict__ Kg,
                                            const unsigned short* __restrict__ Vg,
                                            unsigned short* __restrict__ ctx) {
    __shared__ __attribute__((aligned(16))) unsigned short Ks[64][72];
    __shared__ __attribute__((aligned(16))) unsigned short Vs[64][72];
    __shared__ __attribute__((aligned(16))) unsigned short Pl[128][76];

    const int tid = threadIdx.x, lane = tid & 63, w = tid >> 6;
    const int wq = w * 32;
    const int lg = lane >> 4;        // 16-lane group id 0..3
    const int ll = lane & 15;
    const int bh = blockIdx.x;       // b*16+h
    const int q0 = (gridDim.y - 1 - blockIdx.y) * 128;   // heavy tiles first (LPT)
    const unsigned short* Qh = Qg + (size_t)bh * TSEQ * HD;
    const unsigned short* Kh = Kg + (size_t)bh * TSEQ * HD;
    const unsigned short* Vh = Vg + (size_t)bh * HD * TSEQ;

    // Q B-fragments straight from global: Q[q=wq+rb*16+ll][d=ks*32+lg*8+j]
    short8 qf[2][2];
#pragma unroll
    for (int rb = 0; rb < 2; rb++)
#pragma unroll
        for (int ks = 0; ks < 2; ks++)
            qf[rb][ks] = *(const short8*)(Qh + (size_t)(q0 + wq + rb * 16 + ll) * HD + ks * 32 + lg * 8);

    float mrun[2] = {-1e30f, -1e30f}, lrun[2] = {0.f, 0.f};
    f32x4 zero = {0.f, 0.f, 0.f, 0.f};
    // O^T accumulators: o_t[rb][db], D[row=4lg+r -> d=db*16+4lg+r][col=ll -> q=wq+rb*16+ll]
    f32x4 o_t[2][4];
#pragma unroll
    for (int rb = 0; rb < 2; rb++)
#pragma unroll
        for (int db = 0; db < 4; db++) o_t[rb][db] = zero;

    // async staging: thread covers rows sr and sr+32, 16B each
    const int sr = tid >> 3;          // 0..31
    const int sc = (tid & 7) * 8;     // ushort offset 0..56
    short8 kreg0, kreg1, vreg0, vreg1;
    {
        kreg0 = *(const short8*)(Kh + (size_t)(sr) * HD + sc);
        kreg1 = *(const short8*)(Kh + (size_t)(sr + 32) * HD + sc);
        vreg0 = *(const short8*)(Vh + (size_t)sr * TSEQ + sc);
        vreg1 = *(const short8*)(Vh + (size_t)(sr + 32) * TSEQ + sc);
    }

    const int nkv = q0 / 64 + 2;
    for (int kt = 0; kt < nkv; kt++) {
        const int kv0 = kt * 64;
        // barrier A: all waves done reading previous tile's Ks/Vs
        __builtin_amdgcn_s_barrier();
        __builtin_amdgcn_sched_barrier(0);
        // ds_write staged tile (compiler inserts the vmcnt wait for kreg/vreg data;
        // those loads were issued one full tile ago -> latency already hidden)
        *(short8*)&Ks[sr][sc] = kreg0;
        *(short8*)&Ks[sr + 32][sc] = kreg1;
        *(short8*)&Vs[sr][sc] = vreg0;
        *(short8*)&Vs[sr + 32][sc] = vreg1;
        if (kt + 1 < nkv) {           // issue next tile's loads; they stay in flight across barrier B
            const int nv0 = kv0 + 64;
            kreg0 = *(const short8*)(Kh + (size_t)(nv0 + sr) * HD + sc);
            kreg1 = *(const short8*)(Kh + (size_t)(nv0 + sr + 32) * HD + sc);
            vreg0 = *(const short8*)(Vh + (size_t)sr * TSEQ + nv0 + sc);
            vreg1 = *(const short8*)(Vh + (size_t)(sr + 32) * TSEQ + nv0 + sc);
        }
        __builtin_amdgcn_sched_barrier(0);
        asm volatile("s_waitcnt lgkmcnt(0)" ::: "memory");   // ds_writes drained (NOT vmcnt!)
        __builtin_amdgcn_s_barrier();                         // barrier B: tile visible
        __builtin_amdgcn_sched_barrier(0);

        // S^T = K * Q^T : st[rb][cb], D[row=4lg+r -> kv=cb*16+4lg+r][col=ll -> q]
        f32x4 st[2][4];
#pragma unroll
        for (int rb = 0; rb < 2; rb++)
#pragma unroll
            for (int cb = 0; cb < 4; cb++) st[rb][cb] = zero;
#pragma unroll
        for (int ks = 0; ks < 2; ks++) {
            short8 afrag[4];
#pragma unroll
            for (int cb = 0; cb < 4; cb++)
                afrag[cb] = *(const short8*)&Ks[cb * 16 + ll][ks * 32 + lg * 8];
#pragma unroll
            for (int rb = 0; rb < 2; rb++)
#pragma unroll
                for (int cb = 0; cb < 4; cb++)
                    st[rb][cb] = __builtin_amdgcn_mfma_f32_16x16x32_bf16(afrag[cb], qf[rb][ks], st[rb][cb], 0, 0, 0);
        }

        // causal mask (near-diagonal tiles only)
        if (kv0 + 63 > q0) {
#pragma unroll
            for (int rb = 0; rb < 2; rb++)
#pragma unroll
                for (int cb = 0; cb < 4; cb++)
#pragma unroll
                    for (int r = 0; r < 4; r++) {
                        int kvl = cb * 16 + lg * 4 + r;
                        int ql = wq + rb * 16 + ll;
                        if (kv0 + kvl > q0 + ql) st[rb][cb][r] = -1e30f;
                    }
        }

        // row max: 16 in-register values per (rb), then 2 shfl over the lg axis
        float mx[2];
#pragma unroll
        for (int rb = 0; rb < 2; rb++) {
            float a0 = fmaxf(fmaxf(st[rb][0][0], st[rb][0][1]), fmaxf(st[rb][0][2], st[rb][0][3]));
            float a1 = fmaxf(fmaxf(st[rb][1][0], st[rb][1][1]), fmaxf(st[rb][1][2], st[rb][1][3]));
            float a2 = fmaxf(fmaxf(st[rb][2][0], st[rb][2][1]), fmaxf(st[rb][2][2], st[rb][2][3]));
            float a3 = fmaxf(fmaxf(st[rb][3][0], st[rb][3][1]), fmaxf(st[rb][3][2], st[rb][3][3]));
            float m = fmaxf(fmaxf(a0, a1), fmaxf(a2, a3));
            m = fmaxf(m, __shfl_xor(m, 16));
            m = fmaxf(m, __shfl_xor(m, 32));
            mx[rb] = m;
        }
        // defer-max (THR=8 in exp2 scale -> P <= 256)
        float need = fmaxf(mx[0] - mrun[0], mx[1] - mrun[1]);
        if (__any(need > 8.f)) {
#pragma unroll
            for (int rb = 0; rb < 2; rb++) {
                float mold = mrun[rb];
                float mn = fmaxf(mold, mx[rb]);
                float rs = __builtin_amdgcn_exp2f(mold - mn);
                mrun[rb] = mn;
                lrun[rb] *= rs;
#pragma unroll
                for (int db = 0; db < 4; db++)
#pragma unroll
                    for (int r = 0; r < 4; r++) o_t[rb][db][r] *= rs;
            }
        }
        // P = exp2(S^T - m): lane's 4 consecutive k -> one packed b64 write per (rb,cb)
#pragma unroll
        for (int rb = 0; rb < 2; rb++) {
            float sum = 0.f;
#pragma unroll
            for (int cb = 0; cb < 4; cb++) {
                float p0 = __builtin_amdgcn_exp2f(st[rb][cb][0] - mrun[rb]);
                float p1 = __builtin_amdgcn_exp2f(st[rb][cb][1] - mrun[rb]);
                float p2 = __builtin_amdgcn_exp2f(st[rb][cb][2] - mrun[rb]);
                float p3 = __builtin_amdgcn_exp2f(st[rb][cb][3] - mrun[rb]);
                sum += (p0 + p1) + (p2 + p3);
                uint2 pw;
                pw.x = pk2(p0, p1);
                pw.y = pk2(p2, p3);
                *(uint2*)&Pl[wq + rb * 16 + ll][cb * 16 + lg * 4] = pw;
            }
            sum += __shfl_xor(sum, 16);
            sum += __shfl_xor(sum, 32);
            lrun[rb] += sum;
        }
        // wave-private P: drain this wave's LDS ops, pin ordering (rule 18)
        asm volatile("s_waitcnt lgkmcnt(0)" ::: "memory");
        __builtin_amdgcn_sched_barrier(0);

        // O^T += V^T * P^T : A = Vt-frag, B = P-frag
#pragma unroll
        for (int ks = 0; ks < 2; ks++) {
            short8 pa[2], va[4];
#pragma unroll
            for (int rb = 0; rb < 2; rb++)
                pa[rb] = *(const short8*)&Pl[wq + rb * 16 + ll][ks * 32 + lg * 8];
#pragma unroll
            for (int db = 0; db < 4; db++)
                va[db] = *(const short8*)&Vs[db * 16 + ll][ks * 32 + lg * 8];
#pragma unroll
            for (int rb = 0; rb < 2; rb++)
#pragma unroll
                for (int db = 0; db < 4; db++)
                    o_t[rb][db] = __builtin_amdgcn_mfma_f32_16x16x32_bf16(va[db], pa[rb], o_t[rb][db], 0, 0, 0);
        }
    }

    // epilogue: scale by 1/l (lane-uniform!), transpose O^T via wave-private Pl slice, store
    const int b = bh >> 4, h = bh & 15;
#pragma unroll
    for (int rb = 0; rb < 2; rb++) {
        float linv = 1.f / lrun[rb];
#pragma unroll
        for (int db = 0; db < 4; db++) {
            float v0 = o_t[rb][db][0] * linv, v1 = o_t[rb][db][1] * linv;
            float v2 = o_t[rb][db][2] * linv, v3 = o_t[rb][db][3] * linv;
            uint2 pw;
            pw.x = pk2(v0, v1);
            pw.y = pk2(v2, v3);
            *(uint2*)&Pl[wq + rb * 16 + ll][db * 16 + lg * 4] = pw;
        }
    }
    asm volatile("s_waitcnt lgkmcnt(0)" ::: "memory");
    __builtin_amdgcn_sched_barrier(0);
#pragma unroll
    for (int rb = 0; rb < 2; rb++)
#pragma unroll
        for (int half = 0; half < 2; half++) {
            short8 v = *(const short8*)&Pl[wq + rb * 16 + ll][half * 32 + lg * 8];
            size_t row = (size_t)(b * TSEQ + q0 + wq + rb * 16 + ll);
            *(short8*)(ctx + (row * NH + h) * HD + half * 32 + lg * 8) = v;
        }
}

extern "C" void kernel_launch(void* const* d_in, const int* in_sizes, int n_in,
                              void* d_out, int out_size, void* d_ws, size_t ws_size,
                              hipStream_t stream) {
    const float* x  = (const float*)d_in[0];
    const float* Wq = (const float*)d_in[1];
    const float* Wk = (const float*)d_in[2];
    const float* Wv = (const float*)d_in[3];
    const float* Wo = (const float*)d_in[4];
    const float* bo = (const float*)d_in[5];
    float* out = (float*)d_out;

    char* ws = (char*)d_ws;
    unsigned short* xb   = (unsigned short*)(ws);             // 16,777,216 B
    unsigned short* Wqb  = (unsigned short*)(ws + 16777216);
    unsigned short* Wkb  = (unsigned short*)(ws + 18874368);
    unsigned short* Wvb  = (unsigned short*)(ws + 20971520);
    unsigned short* Wob  = (unsigned short*)(ws + 23068672);
    unsigned short* Qb   = (unsigned short*)(ws + 25165824);  // [B,H,T,hd] bf16 (pre-scaled)
    unsigned short* Kb   = (unsigned short*)(ws + 41943040);  // [B,H,T,hd]
    unsigned short* Vtb  = (unsigned short*)(ws + 58720256);  // [B,H,hd,T]
    unsigned short* ctxb = (unsigned short*)(ws + 75497472);  // [B,T,H,hd]

    cast_f32_bf16<<<8192, 256, 0, stream>>>(x, xb, 2097152);
    cast_f32_bf16<<<1024, 256, 0, stream>>>(Wq, Wqb, 262144);
    cast_f32_bf16<<<1024, 256, 0, stream>>>(Wk, Wkb, 262144);
    cast_f32_bf16<<<1024, 256, 0, stream>>>(Wv, Wvb, 262144);
    cast_f32_bf16<<<1024, 256, 0, stream>>>(Wo, Wob, 262144);

    gemm_qkv<<<dim3(64, 8, 3), 256, 0, stream>>>(xb, Wqb, Wkb, Wvb, Qb, Kb, Vtb);
    attn<<<dim3(64, 16), 256, 0, stream>>>(Qb, Kb, Vtb, ctxb);
    gemm_out<<<dim3(64, 8), 256, 0, stream>>>(ctxb, Wob, bo, out);
}

// Round 6
// 198.375 us; speedup vs baseline: 1.3481x; 1.0323x over previous
//
#include <hip/hip_runtime.h>

#define NH 16
#define HD 64
#define TSEQ 2048
#define DMODEL 1024

typedef __attribute__((ext_vector_type(8))) short short8;
typedef __attribute__((ext_vector_type(4))) float f32x4;

static __device__ __forceinline__ unsigned short f2bf(float f) {
    unsigned u = __builtin_bit_cast(unsigned, f);
    u += 0x7FFF + ((u >> 16) & 1);
    return (unsigned short)(u >> 16);
}

// packed f32x2 -> bf16x2 (low = a, high = b), single VALU op
static __device__ __forceinline__ unsigned cvtpk(float a, float b) {
    unsigned r;
    asm("v_cvt_pk_bf16_f32 %0, %1, %2" : "=v"(r) : "v"(a), "v"(b));
    return r;
}

// ---------------- cast f32 -> bf16 (vectorized) ----------------
__global__ __launch_bounds__(256) void cast_f32_bf16(const float* __restrict__ src,
                                                     unsigned short* __restrict__ dst, int n4) {
    int i = blockIdx.x * 256 + threadIdx.x;
    if (i >= n4) return;
    float4 v = reinterpret_cast<const float4*>(src)[i];
    ushort4 o;
    o.x = f2bf(v.x); o.y = f2bf(v.y); o.z = f2bf(v.z); o.w = f2bf(v.w);
    reinterpret_cast<ushort4*>(dst)[i] = o;
}

// all four weight matrices in one launch (1024 blocks each)
__global__ __launch_bounds__(256) void cast_weights(const float* __restrict__ Wq,
                                                    const float* __restrict__ Wk,
                                                    const float* __restrict__ Wv,
                                                    const float* __restrict__ Wo,
                                                    unsigned short* __restrict__ dq,
                                                    unsigned short* __restrict__ dk,
                                                    unsigned short* __restrict__ dv,
                                                    unsigned short* __restrict__ dwo) {
    int g = blockIdx.x >> 10;
    int i = (blockIdx.x & 1023) * 256 + threadIdx.x;
    const float* s = (g == 0) ? Wq : (g == 1) ? Wk : (g == 2) ? Wv : Wo;
    unsigned short* d = (g == 0) ? dq : (g == 1) ? dk : (g == 2) ? dv : dwo;
    float4 v = reinterpret_cast<const float4*>(s)[i];
    ushort4 o;
    o.x = f2bf(v.x); o.y = f2bf(v.y); o.z = f2bf(v.z); o.w = f2bf(v.w);
    reinterpret_cast<ushort4*>(d)[i] = o;
}

// ---------------- 2-phase dbuf GEMM mainloop: C[128x128] = A[M][K] * Bt[N][K]^T ----------------
// As/Bs are each 2 x 128x32 buffers. One barrier per K-step; next tile's
// global_load_lds stays in flight while current tile computes (T3-lite).
static __device__ __forceinline__ void gemm_mainloop(const unsigned short* __restrict__ A,
                                                     const unsigned short* __restrict__ Bt,
                                                     int m0, int n0, int K,
                                                     unsigned short* As, unsigned short* Bs,
                                                     f32x4 acc[4][4]) {
    const int tid = threadIdx.x;
    const int lane = tid & 63;
    const int w = tid >> 6;
    const int wr = w >> 1, wc = w & 1;
    const int lrow = lane >> 2;          // 0..15
    const int lcol = (lane & 3) * 8;     // 0,8,16,24  (ushort units)

    f32x4 zero = {0.f, 0.f, 0.f, 0.f};
#pragma unroll
    for (int i = 0; i < 4; i++)
#pragma unroll
        for (int j = 0; j < 4; j++) acc[i][j] = zero;

    auto stage = [&](int k0, int buf) {
#pragma unroll
        for (int c = w; c < 8; c += 4) {
            int row = c * 16 + lrow;
            __builtin_amdgcn_global_load_lds(
                (const __attribute__((address_space(1))) void*)(A + (size_t)(m0 + row) * K + k0 + lcol),
                (__attribute__((address_space(3))) void*)(As + buf * 4096 + c * 512), 16, 0, 0);
            __builtin_amdgcn_global_load_lds(
                (const __attribute__((address_space(1))) void*)(Bt + (size_t)(n0 + row) * K + k0 + lcol),
                (__attribute__((address_space(3))) void*)(Bs + buf * 4096 + c * 512), 16, 0, 0);
        }
    };

    stage(0, 0);
    __syncthreads();           // drains vmcnt(0): buf0 ready
    int cur = 0;
    for (int k0 = 0; k0 < K; k0 += 32) {
        if (k0 + 32 < K) stage(k0 + 32, cur ^ 1);   // in flight during compute
        const unsigned short* Ab = As + cur * 4096;
        const unsigned short* Bb = Bs + cur * 4096;
        const int ko = (lane >> 4) * 8;
        short8 a[4], b[4];
#pragma unroll
        for (int i = 0; i < 4; i++)
            a[i] = *(const short8*)(Ab + (wr * 64 + i * 16 + (lane & 15)) * 32 + ko);
#pragma unroll
        for (int j = 0; j < 4; j++)
            b[j] = *(const short8*)(Bb + (wc * 64 + j * 16 + (lane & 15)) * 32 + ko);
#pragma unroll
        for (int i = 0; i < 4; i++)
#pragma unroll
            for (int j = 0; j < 4; j++)
                acc[i][j] = __builtin_amdgcn_mfma_f32_16x16x32_bf16(a[i], b[j], acc[i][j], 0, 0, 0);
        __syncthreads();       // drains vmcnt(0) (next stage landed) + readers done
        cur ^= 1;
    }
}

// ---------------- QKV projection ----------------
// Q is pre-scaled by 0.125 * log2(e) so attention can use exp2 with no per-element scaling.
#define QSCALE 0.180336880f
__global__ __launch_bounds__(256) void gemm_qkv(const unsigned short* __restrict__ xb,
                                                const unsigned short* __restrict__ Wqb,
                                                const unsigned short* __restrict__ Wkb,
                                                const unsigned short* __restrict__ Wvb,
                                                unsigned short* __restrict__ Q,
                                                unsigned short* __restrict__ K,
                                                unsigned short* __restrict__ Vt) {
    __shared__ __attribute__((aligned(16))) unsigned short As[2 * 128 * 32];
    __shared__ __attribute__((aligned(16))) unsigned short Bs[2 * 128 * 32];
    const int m0 = blockIdx.x * 128;
    const int n0 = blockIdx.y * 128;
    const int z = blockIdx.z;
    const unsigned short* Bt = (z == 0) ? Wqb : ((z == 1) ? Wkb : Wvb);
    unsigned short* out = (z == 0) ? Q : ((z == 1) ? K : Vt);

    f32x4 acc[4][4];
    gemm_mainloop(xb, Bt, m0, n0, DMODEL, As, Bs, acc);

    const int tid = threadIdx.x, lane = tid & 63, w = tid >> 6;
    const int wr = w >> 1, wc = w & 1;
    const float sc = (z == 0) ? QSCALE : 1.0f;
#pragma unroll
    for (int i = 0; i < 4; i++)
#pragma unroll
        for (int j = 0; j < 4; j++)
#pragma unroll
            for (int r = 0; r < 4; r++) {
                int row = m0 + wr * 64 + i * 16 + (lane >> 4) * 4 + r;  // b*2048 + t
                int col = n0 + wc * 64 + j * 16 + (lane & 15);          // h*64 + d
                int b = row >> 11, t = row & 2047;
                int h = col >> 6, d = col & 63;
                unsigned short v = f2bf(acc[i][j][r] * sc);
                if (z == 2)
                    out[(((size_t)(b * NH + h)) * HD + d) * TSEQ + t] = v;
                else
                    out[(((size_t)(b * NH + h)) * TSEQ + t) * HD + d] = v;
            }
}

// ---------------- output projection ----------------
__global__ __launch_bounds__(256) void gemm_out(const unsigned short* __restrict__ ctx,
                                                const unsigned short* __restrict__ Wob,
                                                const float* __restrict__ bo,
                                                float* __restrict__ out) {
    __shared__ __attribute__((aligned(16))) unsigned short As[2 * 128 * 32];
    __shared__ __attribute__((aligned(16))) unsigned short Bs[2 * 128 * 32];
    const int m0 = blockIdx.x * 128;
    const int n0 = blockIdx.y * 128;

    f32x4 acc[4][4];
    gemm_mainloop(ctx, Wob, m0, n0, DMODEL, As, Bs, acc);

    const int tid = threadIdx.x, lane = tid & 63, w = tid >> 6;
    const int wr = w >> 1, wc = w & 1;
#pragma unroll
    for (int i = 0; i < 4; i++)
#pragma unroll
        for (int j = 0; j < 4; j++)
#pragma unroll
            for (int r = 0; r < 4; r++) {
                int row = m0 + wr * 64 + i * 16 + (lane >> 4) * 4 + r;
                int col = n0 + wc * 64 + j * 16 + (lane & 15);
                out[(size_t)row * DMODEL + col] = acc[i][j][r] + bo[col];
            }
}

// ---------------- flash attention (causal), Q-tile 128, KV-tile 64, 4 waves ----------------
// S^T structure: st = mfma(K, Q) so q = lane&15 (lane-local rows), k = cb*16+4*lg+r.
// Softmax in-register + 2 shfl. P packed via v_cvt_pk_bf16_f32, b64 LDS writes.
// PV computed as O^T = mfma(Vt-frag, P-frag). Raw s_barrier pipeline (T4).
__global__ __launch_bounds__(256) void attn(const unsigned short* __restrict__ Qg,
                                            const unsigned short* __restrict__ Kg,
                                            const unsigned short* __restrict__ Vg,
                                            unsigned short* __restrict__ ctx) {
    __shared__ __attribute__((aligned(16))) unsigned short Ks[64][72];
    __shared__ __attribute__((aligned(16))) unsigned short Vs[64][72];
    __shared__ __attribute__((aligned(16))) unsigned short Pl[128][76];

    const int tid = threadIdx.x, lane = tid & 63, w = tid >> 6;
    const int wq = w * 32;
    const int lg = lane >> 4;        // 16-lane group id 0..3
    const int ll = lane & 15;
    const int bh = blockIdx.x;       // b*16+h
    const int q0 = (gridDim.y - 1 - blockIdx.y) * 128;   // heavy tiles first (LPT)
    const unsigned short* Qh = Qg + (size_t)bh * TSEQ * HD;
    const unsigned short* Kh = Kg + (size_t)bh * TSEQ * HD;
    const unsigned short* Vh = Vg + (size_t)bh * HD * TSEQ;

    // Q B-fragments straight from global: Q[q=wq+rb*16+ll][d=ks*32+lg*8+j]
    short8 qf[2][2];
#pragma unroll
    for (int rb = 0; rb < 2; rb++)
#pragma unroll
        for (int ks = 0; ks < 2; ks++)
            qf[rb][ks] = *(const short8*)(Qh + (size_t)(q0 + wq + rb * 16 + ll) * HD + ks * 32 + lg * 8);

    float mrun[2] = {-1e30f, -1e30f}, lrun[2] = {0.f, 0.f};
    const f32x4 zerov = {0.f, 0.f, 0.f, 0.f};
    // O^T accumulators: o_t[rb][db], D[row=4lg+r -> d=db*16+4lg+r][col=ll -> q=wq+rb*16+ll]
    f32x4 o_t[2][4];
#pragma unroll
    for (int rb = 0; rb < 2; rb++)
#pragma unroll
        for (int db = 0; db < 4; db++) o_t[rb][db] = zerov;

    // async staging: thread covers rows sr and sr+32, 16B each
    const int sr = tid >> 3;          // 0..31
    const int sc = (tid & 7) * 8;     // ushort offset 0..56
    short8 kreg0, kreg1, vreg0, vreg1;
    {
        kreg0 = *(const short8*)(Kh + (size_t)(sr) * HD + sc);
        kreg1 = *(const short8*)(Kh + (size_t)(sr + 32) * HD + sc);
        vreg0 = *(const short8*)(Vh + (size_t)sr * TSEQ + sc);
        vreg1 = *(const short8*)(Vh + (size_t)(sr + 32) * TSEQ + sc);
    }

    const int nkv = q0 / 64 + 2;
    for (int kt = 0; kt < nkv; kt++) {
        const int kv0 = kt * 64;
        // barrier A: all waves done reading previous tile's Ks/Vs
        __builtin_amdgcn_s_barrier();
        __builtin_amdgcn_sched_barrier(0);
        *(short8*)&Ks[sr][sc] = kreg0;
        *(short8*)&Ks[sr + 32][sc] = kreg1;
        *(short8*)&Vs[sr][sc] = vreg0;
        *(short8*)&Vs[sr + 32][sc] = vreg1;
        if (kt + 1 < nkv) {           // next tile's loads stay in flight across barrier B
            const int nv0 = kv0 + 64;
            kreg0 = *(const short8*)(Kh + (size_t)(nv0 + sr) * HD + sc);
            kreg1 = *(const short8*)(Kh + (size_t)(nv0 + sr + 32) * HD + sc);
            vreg0 = *(const short8*)(Vh + (size_t)sr * TSEQ + nv0 + sc);
            vreg1 = *(const short8*)(Vh + (size_t)(sr + 32) * TSEQ + nv0 + sc);
        }
        __builtin_amdgcn_sched_barrier(0);
        asm volatile("s_waitcnt lgkmcnt(0)" ::: "memory");   // ds_writes drained (NOT vmcnt)
        __builtin_amdgcn_s_barrier();                         // barrier B: tile visible
        __builtin_amdgcn_sched_barrier(0);

        // S^T = K * Q^T : st[rb][cb], D[row=4lg+r -> kv=cb*16+4lg+r][col=ll -> q]
        short8 af0[4], af1[4];
#pragma unroll
        for (int cb = 0; cb < 4; cb++) {
            af0[cb] = *(const short8*)&Ks[cb * 16 + ll][lg * 8];
            af1[cb] = *(const short8*)&Ks[cb * 16 + ll][32 + lg * 8];
        }
        f32x4 st[2][4];
#pragma unroll
        for (int rb = 0; rb < 2; rb++)
#pragma unroll
            for (int cb = 0; cb < 4; cb++)
                st[rb][cb] = __builtin_amdgcn_mfma_f32_16x16x32_bf16(af0[cb], qf[rb][0], zerov, 0, 0, 0);
#pragma unroll
        for (int rb = 0; rb < 2; rb++)
#pragma unroll
            for (int cb = 0; cb < 4; cb++)
                st[rb][cb] = __builtin_amdgcn_mfma_f32_16x16x32_bf16(af1[cb], qf[rb][1], st[rb][cb], 0, 0, 0);

        // causal mask (near-diagonal tiles only)
        if (kv0 + 63 > q0) {
#pragma unroll
            for (int rb = 0; rb < 2; rb++)
#pragma unroll
                for (int cb = 0; cb < 4; cb++)
#pragma unroll
                    for (int r = 0; r < 4; r++) {
                        int kvl = cb * 16 + lg * 4 + r;
                        int ql = wq + rb * 16 + ll;
                        if (kv0 + kvl > q0 + ql) st[rb][cb][r] = -1e30f;
                    }
        }

        // row max: 16 in-register values per (rb), then 2 shfl over the lg axis
        float mx[2];
#pragma unroll
        for (int rb = 0; rb < 2; rb++) {
            float a0 = fmaxf(fmaxf(st[rb][0][0], st[rb][0][1]), fmaxf(st[rb][0][2], st[rb][0][3]));
            float a1 = fmaxf(fmaxf(st[rb][1][0], st[rb][1][1]), fmaxf(st[rb][1][2], st[rb][1][3]));
            float a2 = fmaxf(fmaxf(st[rb][2][0], st[rb][2][1]), fmaxf(st[rb][2][2], st[rb][2][3]));
            float a3 = fmaxf(fmaxf(st[rb][3][0], st[rb][3][1]), fmaxf(st[rb][3][2], st[rb][3][3]));
            float m = fmaxf(fmaxf(a0, a1), fmaxf(a2, a3));
            m = fmaxf(m, __shfl_xor(m, 16));
            m = fmaxf(m, __shfl_xor(m, 32));
            mx[rb] = m;
        }
        // defer-max (THR=8 in exp2 scale -> P <= 256)
        float need = fmaxf(mx[0] - mrun[0], mx[1] - mrun[1]);
        if (__any(need > 8.f)) {
#pragma unroll
            for (int rb = 0; rb < 2; rb++) {
                float mold = mrun[rb];
                float mn = fmaxf(mold, mx[rb]);
                float rs = __builtin_amdgcn_exp2f(mold - mn);
                mrun[rb] = mn;
                lrun[rb] *= rs;
#pragma unroll
                for (int db = 0; db < 4; db++)
#pragma unroll
                    for (int r = 0; r < 4; r++) o_t[rb][db][r] *= rs;
            }
        }
        // P = exp2(S^T - m): packed b64 write per (rb,cb) via v_cvt_pk_bf16_f32
#pragma unroll
        for (int rb = 0; rb < 2; rb++) {
            float sum = 0.f;
#pragma unroll
            for (int cb = 0; cb < 4; cb++) {
                float p0 = __builtin_amdgcn_exp2f(st[rb][cb][0] - mrun[rb]);
                float p1 = __builtin_amdgcn_exp2f(st[rb][cb][1] - mrun[rb]);
                float p2 = __builtin_amdgcn_exp2f(st[rb][cb][2] - mrun[rb]);
                float p3 = __builtin_amdgcn_exp2f(st[rb][cb][3] - mrun[rb]);
                sum += (p0 + p1) + (p2 + p3);
                uint2 pw;
                pw.x = cvtpk(p0, p1);
                pw.y = cvtpk(p2, p3);
                *(uint2*)&Pl[wq + rb * 16 + ll][cb * 16 + lg * 4] = pw;
            }
            sum += __shfl_xor(sum, 16);
            sum += __shfl_xor(sum, 32);
            lrun[rb] += sum;
        }
        // wave-private P: drain this wave's LDS ops, pin ordering (rule 18)
        asm volatile("s_waitcnt lgkmcnt(0)" ::: "memory");
        __builtin_amdgcn_sched_barrier(0);

        // O^T += V^T * P^T : A = Vt-frag, B = P-frag
#pragma unroll
        for (int ks = 0; ks < 2; ks++) {
            short8 pa[2], va[4];
#pragma unroll
            for (int rb = 0; rb < 2; rb++)
                pa[rb] = *(const short8*)&Pl[wq + rb * 16 + ll][ks * 32 + lg * 8];
#pragma unroll
            for (int db = 0; db < 4; db++)
                va[db] = *(const short8*)&Vs[db * 16 + ll][ks * 32 + lg * 8];
#pragma unroll
            for (int rb = 0; rb < 2; rb++)
#pragma unroll
                for (int db = 0; db < 4; db++)
                    o_t[rb][db] = __builtin_amdgcn_mfma_f32_16x16x32_bf16(va[db], pa[rb], o_t[rb][db], 0, 0, 0);
        }
    }

    // epilogue: scale by 1/l (lane-uniform), transpose O^T via wave-private Pl slice, store
    const int b = bh >> 4, h = bh & 15;
#pragma unroll
    for (int rb = 0; rb < 2; rb++) {
        float linv = 1.f / lrun[rb];
#pragma unroll
        for (int db = 0; db < 4; db++) {
            uint2 pw;
            pw.x = cvtpk(o_t[rb][db][0] * linv, o_t[rb][db][1] * linv);
            pw.y = cvtpk(o_t[rb][db][2] * linv, o_t[rb][db][3] * linv);
            *(uint2*)&Pl[wq + rb * 16 + ll][db * 16 + lg * 4] = pw;
        }
    }
    asm volatile("s_waitcnt lgkmcnt(0)" ::: "memory");
    __builtin_amdgcn_sched_barrier(0);
#pragma unroll
    for (int rb = 0; rb < 2; rb++)
#pragma unroll
        for (int half = 0; half < 2; half++) {
            short8 v = *(const short8*)&Pl[wq + rb * 16 + ll][half * 32 + lg * 8];
            size_t row = (size_t)(b * TSEQ + q0 + wq + rb * 16 + ll);
            *(short8*)(ctx + (row * NH + h) * HD + half * 32 + lg * 8) = v;
        }
}

extern "C" void kernel_launch(void* const* d_in, const int* in_sizes, int n_in,
                              void* d_out, int out_size, void* d_ws, size_t ws_size,
                              hipStream_t stream) {
    const float* x  = (const float*)d_in[0];
    const float* Wq = (const float*)d_in[1];
    const float* Wk = (const float*)d_in[2];
    const float* Wv = (const float*)d_in[3];
    const float* Wo = (const float*)d_in[4];
    const float* bo = (const float*)d_in[5];
    float* out = (float*)d_out;

    char* ws = (char*)d_ws;
    unsigned short* xb   = (unsigned short*)(ws);             // 16,777,216 B
    unsigned short* Wqb  = (unsigned short*)(ws + 16777216);
    unsigned short* Wkb  = (unsigned short*)(ws + 18874368);
    unsigned short* Wvb  = (unsigned short*)(ws + 20971520);
    unsigned short* Wob  = (unsigned short*)(ws + 23068672);
    unsigned short* Qb   = (unsigned short*)(ws + 25165824);  // [B,H,T,hd] bf16 (pre-scaled)
    unsigned short* Kb   = (unsigned short*)(ws + 41943040);  // [B,H,T,hd]
    unsigned short* Vtb  = (unsigned short*)(ws + 58720256);  // [B,H,hd,T]
    unsigned short* ctxb = (unsigned short*)(ws + 75497472);  // [B,T,H,hd]

    cast_f32_bf16<<<8192, 256, 0, stream>>>(x, xb, 2097152);
    cast_weights<<<4096, 256, 0, stream>>>(Wq, Wk, Wv, Wo, Wqb, Wkb, Wvb, Wob);

    gemm_qkv<<<dim3(64, 8, 3), 256, 0, stream>>>(xb, Wqb, Wkb, Wvb, Qb, Kb, Vtb);
    attn<<<dim3(64, 16), 256, 0, stream>>>(Qb, Kb, Vtb, ctxb);
    gemm_out<<<dim3(64, 8), 256, 0, stream>>>(ctxb, Wob, bo, out);
}